// Round 5
// baseline (250.291 us; speedup 1.0000x reference)
//
#include <hip/hip_runtime.h>

// BrewCnnLayer v4: two-kernel pipeline through d_ws.
//   A: conv1 (7x7, 1->10) + relu + ratio1; h1 (rows padded 22->24) -> d_ws
//   B: conv2 (5x5, 10->10) + relu + ratio2, h1 staged to LDS per image
// out = [ h2 (b*3240) | rat1 (b*4840) | rat2 (b*3240) ]  (f32)
//
// Rationale (R3 post-mortem): fused one-block-per-image is occupancy-starved
// (24 KB LDS + barrier phases -> 23% occupancy, stalls exposed). Split gives
// A ~75% / B ~50% occupancy, no divergence (clamped task ids -> duplicate
// lanes write identical values), thread-uniform weight addresses (s_load),
// fp32 vector math (no fp32 MFMA on CDNA4; bf16 flips ratio signs).
// Fallback: known-good fused kernel if ws_size < h1 buffer size.

#define TA 128
#define TB 128

__global__ __launch_bounds__(TA, 4) void brew_conv1(
    const float* __restrict__ x,    // (nimg, 784)
    const float* __restrict__ Wa,   // (10, 49)
    float* __restrict__ out,
    float* __restrict__ h1,         // (nimg, 10, 22, 24) padded
    int nimg)
{
    __shared__ __align__(16) float s_x[784];
    const int img = blockIdx.x;
    const int tid = threadIdx.x;

    {
        const float4* xin = reinterpret_cast<const float4*>(x + img * 784);
        float4* sx = reinterpret_cast<float4*>(s_x);
        for (int i = tid; i < 196; i += TA) sx[i] = xin[i];
    }
    __syncthreads();

    // task = (row 0..21, col-group of 5 starting {0,5,10,15,17}); clamp dups
    const int t   = tid < 110 ? tid : 109;
    const int row = t / 5;
    const int g   = t - row * 5;
    const int c   = (g < 4) ? 5 * g : 17;

    float acc[10][5];
#pragma unroll
    for (int oc = 0; oc < 10; ++oc)
#pragma unroll
        for (int k = 0; k < 5; ++k) acc[oc][k] = 0.0f;

#pragma unroll 1
    for (int ky = 0; ky < 7; ++ky) {
        float in[11];
        const float* rp = s_x + (row + ky) * 28 + c;
#pragma unroll
        for (int j = 0; j < 11; ++j) in[j] = rp[j];

#pragma unroll
        for (int oc = 0; oc < 10; ++oc) {
            const float* wp = Wa + oc * 49 + ky * 7;   // thread-uniform -> s_load
#pragma unroll
            for (int kx = 0; kx < 7; ++kx) {
                const float w = wp[kx];
#pragma unroll
                for (int k = 0; k < 5; ++k)
                    acc[oc][k] = fmaf(in[k + kx], w, acc[oc][k]);
            }
        }
    }

    const int r1_base = nimg * 3240 + img * 4840;
    float* hb = h1 + img * 5280;
#pragma unroll
    for (int oc = 0; oc < 10; ++oc) {
        float* hp = hb + oc * 528 + row * 24 + c;
        float* rp = out + r1_base + oc * 484 + row * 22 + c;
#pragma unroll
        for (int k = 0; k < 5; ++k) {
            const float h = acc[oc][k];
            hp[k] = h > 0.0f ? h : 0.0f;
            rp[k] = h > 0.0f ? 1.0f : 0.0f;
        }
    }
}

__global__ __launch_bounds__(TB, 4) void brew_conv2(
    const float* __restrict__ h1,   // (nimg, 10, 22, 24)
    const float* __restrict__ Wb,   // (10, 250) = (10,10,5,5) OIHW
    float* __restrict__ out,
    int nimg)
{
    __shared__ __align__(16) float s_h[10 * 528];   // 21120 B
    const int img = blockIdx.x;
    const int tid = threadIdx.x;

    {   // pure float4 copy: 5280 floats = 1320 float4
        const float4* src = reinterpret_cast<const float4*>(h1 + img * 5280);
        float4* dst = reinterpret_cast<float4*>(s_h);
        for (int i = tid; i < 1320; i += TB) dst[i] = src[i];
    }
    __syncthreads();

    // task = (row 0..17, col-group of 3); clamp dups
    const int t   = tid < 108 ? tid : 107;
    const int row = t / 6;
    const int c   = 3 * (t - row * 6);

    float acc[10][3];
#pragma unroll
    for (int oc = 0; oc < 10; ++oc)
#pragma unroll
        for (int k = 0; k < 3; ++k) acc[oc][k] = 0.0f;

#pragma unroll 1
    for (int ic = 0; ic < 10; ++ic) {
        const float* hb = s_h + ic * 528 + row * 24 + c;
#pragma unroll
        for (int ky = 0; ky < 5; ++ky) {
            float in[7];
            const float* rp = hb + ky * 24;
#pragma unroll
            for (int j = 0; j < 7; ++j) in[j] = rp[j];

#pragma unroll
            for (int oc = 0; oc < 10; ++oc) {
                const float* wp = Wb + oc * 250 + ic * 25 + ky * 5;  // uniform
#pragma unroll
                for (int kx = 0; kx < 5; ++kx) {
                    const float w = wp[kx];
#pragma unroll
                    for (int k = 0; k < 3; ++k)
                        acc[oc][k] = fmaf(in[k + kx], w, acc[oc][k]);
                }
            }
        }
    }

    const int h2_base = img * 3240;
    const int r2_base = nimg * 8080 + img * 3240;
#pragma unroll
    for (int oc = 0; oc < 10; ++oc) {
        float* h2p = out + h2_base + oc * 324 + row * 18 + c;
        float* r2p = out + r2_base + oc * 324 + row * 18 + c;
#pragma unroll
        for (int k = 0; k < 3; ++k) {
            const float h = acc[oc][k];
            h2p[k] = h > 0.0f ? h : 0.0f;
            r2p[k] = h > 0.0f ? 1.0f : 0.0f;
        }
    }
}

// ---- fallback: known-good fused kernel (R2) if ws too small ----
__global__ __launch_bounds__(256, 4) void brewcnn_fused_fb(
    const float* __restrict__ x, const float* __restrict__ Wa,
    const float* __restrict__ Wb, float* __restrict__ out, int nimg)
{
    __shared__ __align__(16) float s_x[28 * 28];
    __shared__ __align__(16) float s_h[10][22 * 24];
    __shared__ __align__(16) float s_wa[490];
    __shared__ __align__(16) float s_wb[2500];

    const int img = blockIdx.x;
    const int tid = threadIdx.x;

    if (tid < 196)
        reinterpret_cast<float4*>(s_x)[tid] =
            reinterpret_cast<const float4*>(x + img * 784)[tid];
    if (tid < 122)
        reinterpret_cast<float4*>(s_wa)[tid] =
            reinterpret_cast<const float4*>(Wa)[tid];
    if (tid < 2) s_wa[488 + tid] = Wa[488 + tid];
    for (int i = tid; i < 625; i += 256)
        reinterpret_cast<float4*>(s_wb)[i] = reinterpret_cast<const float4*>(Wb)[i];
    __syncthreads();

    const int h2_base = img * 3240;
    const int r1_base = nimg * 3240 + img * 4840;
    const int r2_base = nimg * 8080 + img * 3240;

    if (tid < 220) {
        const int row = tid / 10, oc = tid - row * 10;
        float acc[22];
#pragma unroll
        for (int i = 0; i < 22; ++i) acc[i] = 0.0f;
        const float* wrow = s_wa + oc * 49;
        for (int ky = 0; ky < 7; ++ky) {
            float in[28];
            const float4* rp = reinterpret_cast<const float4*>(s_x + (row + ky) * 28);
#pragma unroll
            for (int j = 0; j < 7; ++j) {
                float4 v = rp[j];
                in[4*j] = v.x; in[4*j+1] = v.y; in[4*j+2] = v.z; in[4*j+3] = v.w;
            }
            float w[7];
#pragma unroll
            for (int k = 0; k < 7; ++k) w[k] = wrow[ky * 7 + k];
#pragma unroll
            for (int kx = 0; kx < 7; ++kx)
#pragma unroll
                for (int px = 0; px < 22; ++px)
                    acc[px] = fmaf(in[px + kx], w[kx], acc[px]);
        }
        float r1v[22];
#pragma unroll
        for (int px = 0; px < 22; ++px) {
            const float h = acc[px];
            acc[px] = h > 0.0f ? h : 0.0f;
            r1v[px] = h > 0.0f ? 1.0f : 0.0f;
        }
        float* hdst = &s_h[oc][row * 24];
#pragma unroll
        for (int j = 0; j < 5; ++j)
            reinterpret_cast<float4*>(hdst)[j] =
                make_float4(acc[4*j], acc[4*j+1], acc[4*j+2], acc[4*j+3]);
        hdst[20] = acc[20]; hdst[21] = acc[21];
        float* r1p = out + r1_base + oc * 484 + row * 22;
#pragma unroll
        for (int j = 0; j < 11; ++j)
            reinterpret_cast<float2*>(r1p)[j] = make_float2(r1v[2*j], r1v[2*j+1]);
    }
    __syncthreads();

    if (tid < 180) {
        const int row = tid / 10, oc = tid - row * 10;
        float acc[18];
#pragma unroll
        for (int i = 0; i < 18; ++i) acc[i] = 0.0f;
        const float* wbase = s_wb + oc * 250;
#pragma unroll 1
        for (int ic = 0; ic < 10; ++ic) {
            const float* hbase = &s_h[ic][0];
            const float* wic = wbase + ic * 25;
            for (int ky = 0; ky < 5; ++ky) {
                float in[24];
                const float4* rp = reinterpret_cast<const float4*>(hbase + (row + ky) * 24);
#pragma unroll
                for (int j = 0; j < 6; ++j) {
                    float4 v = rp[j];
                    in[4*j] = v.x; in[4*j+1] = v.y; in[4*j+2] = v.z; in[4*j+3] = v.w;
                }
                float w[5];
#pragma unroll
                for (int k = 0; k < 5; ++k) w[k] = wic[ky * 5 + k];
#pragma unroll
                for (int kx = 0; kx < 5; ++kx)
#pragma unroll
                    for (int px = 0; px < 18; ++px)
                        acc[px] = fmaf(in[px + kx], w[kx], acc[px]);
            }
        }
        float hv[18], rv[18];
#pragma unroll
        for (int px = 0; px < 18; ++px) {
            const float h = acc[px];
            hv[px] = h > 0.0f ? h : 0.0f;
            rv[px] = h > 0.0f ? 1.0f : 0.0f;
        }
        float* h2p = out + h2_base + oc * 324 + row * 18;
        float* r2p = out + r2_base + oc * 324 + row * 18;
#pragma unroll
        for (int j = 0; j < 9; ++j) {
            reinterpret_cast<float2*>(h2p)[j] = make_float2(hv[2*j], hv[2*j+1]);
            reinterpret_cast<float2*>(r2p)[j] = make_float2(rv[2*j], rv[2*j+1]);
        }
    }
}

extern "C" void kernel_launch(void* const* d_in, const int* in_sizes, int n_in,
                              void* d_out, int out_size, void* d_ws, size_t ws_size,
                              hipStream_t stream) {
    const float* x  = (const float*)d_in[0];
    const float* Wa = (const float*)d_in[1];
    const float* Wb = (const float*)d_in[2];
    float* out = (float*)d_out;
    const int nimg = in_sizes[0] / 784;

    const size_t h1_bytes = (size_t)nimg * 5280 * sizeof(float);  // ~43.3 MB @ 2048
    if (ws_size >= h1_bytes) {
        float* h1 = (float*)d_ws;
        brew_conv1<<<nimg, TA, 0, stream>>>(x, Wa, out, h1, nimg);
        brew_conv2<<<nimg, TB, 0, stream>>>(h1, Wb, out, nimg);
    } else {
        brewcnn_fused_fb<<<nimg, 256, 0, stream>>>(x, Wa, Wb, out, nimg);
    }
}

// Round 7
// 179.662 us; speedup vs baseline: 1.3931x; 1.3931x over previous
//
#include <hip/hip_runtime.h>

// BrewCnnLayer v6b: fused, one 256-thread block per image, weights ALL in LDS
// (R1/R5 evidence: uniform global s_loads mixed with ds_reads stall on shared
// lgkmcnt drains). DS-instruction economy via per-ic register-stationary
// weights: conv2 = 37 DS instrs per 450 FMA wave-instrs (vs R2's 55/450).
// Bank layout: s_h oc-stride 532 (2-way max), s_wb [oc][ic][28] oc-stride 284
// (2-way max), s_x row stride 28 (conflict-free). fp32 vector math (no fp32
// MFMA on CDNA4; bf16 flips ratio signs near zero).
// v6 bug fixed: s_wa staging guard gave only 60 of 122 float4s -> poison -> inf.
// out = [ h2 (b*3240) | rat1 (b*4840) | rat2 (b*3240) ]  (f32)

#define THREADS 256

__global__ __launch_bounds__(THREADS, 4) void brewcnn_v6(
    const float* __restrict__ x,    // (nimg, 784)
    const float* __restrict__ Wa,   // (10, 49)
    const float* __restrict__ Wb,   // (10, 250)
    float* __restrict__ out,
    int nimg)
{
    __shared__ __align__(16) float s_x[784];        // 3136 B
    __shared__ __align__(16) float s_h[10 * 532];   // 21280 B: [oc]*532 + row*24 + col
    __shared__ __align__(16) float s_wa[492];       // 1968 B
    __shared__ __align__(16) float s_wb[2840];      // 11360 B: [oc]*284 + [ic]*28 + k
                                                    // total ~37.8 KB -> 4 blocks/CU
    const int img = blockIdx.x;
    const int tid = threadIdx.x;

    // ---- stage x, Wa, Wb (Wb re-laid-out padded for aligned b128 + bank spread)
    if (tid < 196)
        reinterpret_cast<float4*>(s_x)[tid] =
            reinterpret_cast<const float4*>(x + img * 784)[tid];
    if (tid < 122)
        reinterpret_cast<float4*>(s_wa)[tid] =
            reinterpret_cast<const float4*>(Wa)[tid];
    if (tid == 196) { s_wa[488] = Wa[488]; s_wa[489] = Wa[489]; }
    for (int t = tid; t < 2500; t += THREADS) {
        const int oc  = t / 250;
        const int rem = t - oc * 250;
        const int ic  = rem / 25;
        const int k   = rem - ic * 25;
        s_wb[oc * 284 + ic * 28 + k] = Wb[t];
    }
    __syncthreads();

    const int h2_base = img * 3240;
    const int r1_base = nimg * 3240 + img * 4840;
    const int r2_base = nimg * 8080 + img * 3240;

    // ---- conv1: task = (row 0..21, oc 0..9), 220 tasks (clamped dups benign)
    {
        const int t   = tid < 220 ? tid : 219;
        const int row = t / 10;
        const int oc  = t - row * 10;

        float acc[22];
#pragma unroll
        for (int i = 0; i < 22; ++i) acc[i] = 0.0f;

        const float* wrow = s_wa + oc * 49;
#pragma unroll 1
        for (int ky = 0; ky < 7; ++ky) {
            float in[28];
            const float4* rp = reinterpret_cast<const float4*>(s_x + (row + ky) * 28);
#pragma unroll
            for (int j = 0; j < 7; ++j) {
                const float4 v = rp[j];
                in[4*j+0] = v.x; in[4*j+1] = v.y; in[4*j+2] = v.z; in[4*j+3] = v.w;
            }
            float w[7];
#pragma unroll
            for (int k = 0; k < 7; ++k) w[k] = wrow[ky * 7 + k];
#pragma unroll
            for (int kx = 0; kx < 7; ++kx)
#pragma unroll
                for (int px = 0; px < 22; ++px)
                    acc[px] = fmaf(in[px + kx], w[kx], acc[px]);
        }

        float r1v[22];
#pragma unroll
        for (int px = 0; px < 22; ++px) {
            const float h = acc[px];
            acc[px] = h > 0.0f ? h : 0.0f;
            r1v[px] = h > 0.0f ? 1.0f : 0.0f;
        }
        float* hdst = s_h + oc * 532 + row * 24;
#pragma unroll
        for (int j = 0; j < 5; ++j)
            reinterpret_cast<float4*>(hdst)[j] =
                make_float4(acc[4*j], acc[4*j+1], acc[4*j+2], acc[4*j+3]);
        hdst[20] = acc[20];
        hdst[21] = acc[21];

        float* r1p = out + r1_base + oc * 484 + row * 22;
#pragma unroll
        for (int j = 0; j < 11; ++j)
            reinterpret_cast<float2*>(r1p)[j] = make_float2(r1v[2*j], r1v[2*j+1]);
    }
    __syncthreads();

    // ---- conv2: task = (row 0..17, oc 0..9), 180 tasks; per-ic reg weights
    {
        const int t   = tid < 180 ? tid : 179;
        const int row = t / 10;
        const int oc  = t - row * 10;

        float acc[18];
#pragma unroll
        for (int i = 0; i < 18; ++i) acc[i] = 0.0f;

#pragma unroll 1
        for (int ic = 0; ic < 10; ++ic) {
            float w[28];
            const float4* wp = reinterpret_cast<const float4*>(s_wb + oc * 284 + ic * 28);
#pragma unroll
            for (int j = 0; j < 7; ++j) {
                const float4 v = wp[j];
                w[4*j+0] = v.x; w[4*j+1] = v.y; w[4*j+2] = v.z; w[4*j+3] = v.w;
            }
            const float* hb = s_h + ic * 532 + row * 24;
#pragma unroll
            for (int ky = 0; ky < 5; ++ky) {
                float in[24];
                const float4* rp = reinterpret_cast<const float4*>(hb + ky * 24);
#pragma unroll
                for (int j = 0; j < 6; ++j) {
                    const float4 v = rp[j];
                    in[4*j+0] = v.x; in[4*j+1] = v.y; in[4*j+2] = v.z; in[4*j+3] = v.w;
                }
#pragma unroll
                for (int kx = 0; kx < 5; ++kx)
#pragma unroll
                    for (int px = 0; px < 18; ++px)
                        acc[px] = fmaf(in[px + kx], w[ky * 5 + kx], acc[px]);
            }
        }

        float hv[18], rv[18];
#pragma unroll
        for (int px = 0; px < 18; ++px) {
            const float h = acc[px];
            hv[px] = h > 0.0f ? h : 0.0f;
            rv[px] = h > 0.0f ? 1.0f : 0.0f;
        }
        float* h2p = out + h2_base + oc * 324 + row * 18;
        float* r2p = out + r2_base + oc * 324 + row * 18;
#pragma unroll
        for (int j = 0; j < 9; ++j) {
            reinterpret_cast<float2*>(h2p)[j] = make_float2(hv[2*j], hv[2*j+1]);
            reinterpret_cast<float2*>(r2p)[j] = make_float2(rv[2*j], rv[2*j+1]);
        }
    }
}

extern "C" void kernel_launch(void* const* d_in, const int* in_sizes, int n_in,
                              void* d_out, int out_size, void* d_ws, size_t ws_size,
                              hipStream_t stream) {
    const float* x  = (const float*)d_in[0];
    const float* Wa = (const float*)d_in[1];
    const float* Wb = (const float*)d_in[2];
    float* out = (float*)d_out;
    const int nimg = in_sizes[0] / 784;

    brewcnn_v6<<<nimg, THREADS, 0, stream>>>(x, Wa, Wb, out, nimg);
}